// Round 12
// baseline (280.895 us; speedup 1.0000x reference)
//
#include <hip/hip_runtime.h>
#include <math.h>

// Problem constants
#define TT 16384   // tokens
#define HH 2048    // hidden
#define EE 64      // experts
#define KK 8       // top_k

#define TB 16          // tokens per block (one MFMA M-tile)
#define HCK 32         // h per chunk (ONE MFMA k-step)
#define NC2 (HH / HCK) // 64 chunks
#define TOPC 10        // fp32 candidate count for fixup
#define MARGIN 2.5e-5f // selection-score gap below which we fp64-verify

// Output layout (flat float32):
// probs [TT][KK] | indices [TT][KK] | map [TT][EE] | aux scalar
#define IDX_OFF ((size_t)TT * KK)
#define MAP_OFF ((size_t)2 * TT * KK)
#define AUX_OFF ((size_t)2 * TT * KK + (size_t)TT * EE)

// d_ws layout (bf16 shorts): hi plane then lo plane, each WSPLANE shorts.
// Fragment-native: [m (k/32)][kq][e][8 j] -> element (e, k=m*32+kq*8+j)
// at  m*2048 + kq*512 + e*8 + j.  (R10/R11-validated.)
#define WSPLANE 131072

typedef short bf16x8 __attribute__((ext_vector_type(8)));
typedef float f32x4  __attribute__((ext_vector_type(4)));

__device__ __forceinline__ unsigned short f2bf(float x) {   // RNE fp32->bf16
    unsigned int u = __float_as_uint(x);
    u += 0x7FFFu + ((u >> 16) & 1u);
    return (unsigned short)(u >> 16);
}
__device__ __forceinline__ float bf2f(unsigned short b) {
    return __uint_as_float(((unsigned int)b) << 16);
}
__device__ __forceinline__ void cvt4(const float4 v, ushort4* hi, ushort4* lo) {
    unsigned short h0 = f2bf(v.x), h1 = f2bf(v.y),
                   h2 = f2bf(v.z), h3 = f2bf(v.w);
    *hi = make_ushort4(h0, h1, h2, h3);
    *lo = make_ushort4(f2bf(v.x - bf2f(h0)), f2bf(v.y - bf2f(h1)),
                       f2bf(v.z - bf2f(h2)), f2bf(v.w - bf2f(h3)));
}
// 8 consecutive fp32 -> hi/lo bf16x8 fragments, in registers
__device__ __forceinline__ void cvt8(const float4 a, const float4 b,
                                     bf16x8* hi, bf16x8* lo) {
    const float v[8] = {a.x, a.y, a.z, a.w, b.x, b.y, b.z, b.w};
    bf16x8 h, l;
    #pragma unroll
    for (int i = 0; i < 8; ++i) {
        unsigned short hb = f2bf(v[i]);
        h[i] = (short)hb;
        l[i] = (short)f2bf(v[i] - bf2f(hb));
    }
    *hi = h; *lo = l;
}

// ---- prep: gate_w fp32 -> bf16 hi/lo planes in fragment-native layout ----
__global__ __launch_bounds__(256)
void prep_kernel(const float* __restrict__ gw, unsigned short* __restrict__ ws)
{
    const int gid = blockIdx.x * 256 + threadIdx.x;   // 0..32767 float4 slots
    const int e  = gid >> 9;          // 512 float4 per expert row
    const int k  = (gid & 511) * 4;
    float4 v = *(const float4*)(gw + (size_t)e * HH + k);
    ushort4 hi, lo;
    cvt4(v, &hi, &lo);
    const int off = (k >> 5) * 2048 + ((k >> 3) & 3) * 512 + e * 8 + (k & 7);
    *(ushort4*)(ws + off)           = hi;
    *(ushort4*)(ws + WSPLANE + off) = lo;
}

// ---- 4-slot modulo-scheduled ring (static names, rule #20) ----
// LOAD: issue 4 loads for chunk C into slot S (address-clamped for tail).
#define LOAD_SLOT(S, C)                                                        \
  do {                                                                         \
    const int c_ = (C);                                                        \
    const int cc_ = (c_ < NC2) ? c_ : 0;  /* tail: garbage, never consumed */  \
    const float* hp_ = hgp + cc_ * HCK;                                        \
    h0_##S = *(const float4*)(hp_);                                            \
    h1_##S = *(const float4*)(hp_ + 4);                                        \
    const unsigned short* bp_ = bBase + (size_t)cc_ * 2048;                    \
    bh_##S = *(const bf16x8*)(bp_);                                            \
    bl_##S = *(const bf16x8*)(bp_ + WSPLANE);                                  \
  } while (0)

// USE: copy slot to locals, IMMEDIATELY reissue slot loads for C+4
// (program-order before compute -> issue-early), then cvt + 3 MFMA.
#define USE_SLOT(S, C)                                                         \
  do {                                                                         \
    float4 h0_ = h0_##S, h1_ = h1_##S;                                         \
    bf16x8 bh_ = bh_##S, bl_ = bl_##S;                                         \
    LOAD_SLOT(S, (C) + 4);                                                     \
    bf16x8 Ah_, Al_;                                                           \
    cvt8(h0_, h1_, &Ah_, &Al_);                                                \
    acc = __builtin_amdgcn_mfma_f32_16x16x32_bf16(Ah_, bl_, acc, 0, 0, 0);     \
    acc = __builtin_amdgcn_mfma_f32_16x16x32_bf16(Al_, bh_, acc, 0, 0, 0);     \
    acc = __builtin_amdgcn_mfma_f32_16x16x32_bf16(Ah_, bh_, acc, 0, 0, 0);     \
  } while (0)

__global__ __launch_bounds__(256, 3)
void router_kernel(const float* __restrict__ hidden,
                   const float* __restrict__ gate_w,
                   const float* __restrict__ bias,
                   const unsigned short* __restrict__ wsbuf,
                   float* __restrict__ out)
{
    __shared__ __align__(16) float lg[16 * 68 + 8];   // logit exchange only

    const int tid  = threadIdx.x;
    const int tok0 = blockIdx.x * TB;

    // fragment coords (R9/R10/R11-validated)
    const int lane = tid & 63;
    const int e0   = (tid >> 6) * 16;   // wave's expert tile
    const int rx   = lane & 15;
    const int kq   = lane >> 4;

    const float* hgp = hidden + (size_t)(tok0 + rx) * HH + kq * 8;
    const unsigned short* bBase = wsbuf + kq * 512 + (e0 + rx) * 8;

    f32x4 acc = {0.f, 0.f, 0.f, 0.f};

    // ring slots (static names)
    float4 h0_0, h1_0, h0_1, h1_1, h0_2, h1_2, h0_3, h1_3;
    bf16x8 bh_0, bl_0, bh_1, bl_1, bh_2, bl_2, bh_3, bl_3;

    LOAD_SLOT(0, 0);
    LOAD_SLOT(1, 1);
    LOAD_SLOT(2, 2);
    LOAD_SLOT(3, 3);

    for (int cb = 0; cb < NC2; cb += 4) {
        USE_SLOT(0, cb + 0);
        USE_SLOT(1, cb + 1);
        USE_SLOT(2, cb + 2);
        USE_SLOT(3, cb + 3);
    }

    // ---- logits to LDS: row = token = 4*kq + r, col = expert = e0 + rx ----
    #pragma unroll
    for (int r = 0; r < 4; ++r)
        lg[(4 * kq + r) * 68 + e0 + rx] = acc[r];
    __syncthreads();

    // ---- epilogue: 16 lanes per token (validated machinery) ----
    const int t   = tid >> 4;   // 0..15
    const int q   = tid & 15;   // lane owns experts q + 16i, i=0..3
    const int tok = tok0 + t;

    float lv[4];
    #pragma unroll
    for (int i = 0; i < 4; ++i) lv[i] = lg[t * 68 + q + 16 * i];

    float mx = lv[0];
    #pragma unroll
    for (int i = 1; i < 4; ++i) mx = fmaxf(mx, lv[i]);
    #pragma unroll
    for (int sh = 1; sh < 16; sh <<= 1) mx = fmaxf(mx, __shfl_xor(mx, sh, 64));

    float ex[4], psum = 0.0f;
    #pragma unroll
    for (int i = 0; i < 4; ++i) { ex[i] = expf(lv[i] - mx); psum += ex[i]; }
    #pragma unroll
    for (int sh = 1; sh < 16; sh <<= 1) psum += __shfl_xor(psum, sh, 64);
    const float inv = 1.0f / psum;

    float pr[4], selv[4];
    #pragma unroll
    for (int i = 0; i < 4; ++i) {
        pr[i]   = ex[i] * inv;
        selv[i] = pr[i] + bias[q + 16 * i];
    }

    // top-10 candidates (fp32), strict-> with lowest-index tie-break
    float ws_[TOPC], wp[TOPC];
    int   wi[TOPC];
    #pragma unroll
    for (int k = 0; k < TOPC; ++k) {
        float bs = selv[0], bp = pr[0];
        int bi = q;
        #pragma unroll
        for (int i = 1; i < 4; ++i)
            if (selv[i] > bs) { bs = selv[i]; bp = pr[i]; bi = q + 16 * i; }
        #pragma unroll
        for (int sh = 1; sh < 16; sh <<= 1) {
            float os = __shfl_xor(bs, sh, 64);
            float op = __shfl_xor(bp, sh, 64);
            int   ob = __shfl_xor(bi, sh, 64);
            if (os > bs || (os == bs && ob < bi)) { bs = os; bp = op; bi = ob; }
        }
        ws_[k] = bs; wp[k] = bp; wi[k] = bi;
        #pragma unroll
        for (int i = 0; i < 4; ++i)
            if (q + 16 * i == bi) selv[i] = -INFINITY;
    }

    // flag: any adjacent gap among ranks 1..9 too small to trust bf16x3
    bool flag = false;
    #pragma unroll
    for (int k = 0; k < 8; ++k)
        flag = flag || (ws_[k] - ws_[k + 1] < MARGIN);

    if (flag) {   // uniform across the 16-lane token group
        const float* hrow = hidden + (size_t)tok * HH;
        const float* wr_[TOPC];
        #pragma unroll
        for (int k = 0; k < TOPC; ++k) wr_[k] = gate_w + (size_t)wi[k] * HH;

        double l64[TOPC];
        #pragma unroll
        for (int k = 0; k < TOPC; ++k) l64[k] = 0.0;

        for (int m = 0; m < 32; ++m) {
            float4 h4 = *(const float4*)(hrow + m * 64 + 4 * q);
            double h0 = h4.x, h1 = h4.y, h2 = h4.z, h3 = h4.w;
            #pragma unroll
            for (int k = 0; k < TOPC; ++k) {
                float4 w4 = *(const float4*)(wr_[k] + m * 64 + 4 * q);
                l64[k] = fma(h0, (double)w4.x, l64[k]);
                l64[k] = fma(h1, (double)w4.y, l64[k]);
                l64[k] = fma(h2, (double)w4.z, l64[k]);
                l64[k] = fma(h3, (double)w4.w, l64[k]);
            }
        }
        #pragma unroll
        for (int k = 0; k < TOPC; ++k)
            #pragma unroll
            for (int sh = 1; sh < 16; sh <<= 1)
                l64[k] += __shfl_xor(l64[k], sh, 64);

        // exact-rank selection scores (common positive rescale; bias exact)
        double s64[TOPC];
        #pragma unroll
        for (int k = 0; k < TOPC; ++k)
            s64[k] = exp(l64[k] - (double)mx) * (double)inv + (double)bias[wi[k]];

        // order first 8 by (score desc, idx asc) - static indices only
        #pragma unroll
        for (int a = 0; a < 8; ++a) {
            #pragma unroll
            for (int b = a + 1; b < TOPC; ++b) {
                bool sw = (s64[b] > s64[a]) ||
                          (s64[b] == s64[a] && wi[b] < wi[a]);
                if (sw) {
                    double td = s64[a]; s64[a] = s64[b]; s64[b] = td;
                    int    ti = wi[a];  wi[a]  = wi[b];  wi[b]  = ti;
                    float  tp = wp[a];  wp[a]  = wp[b];  wp[b]  = tp;
                }
            }
        }
    }

    // ---- common write-out (wi/wp[0..7] final) ----
    int oi = wi[0];
    float opf = wp[0];
    #pragma unroll
    for (int k = 1; k < 8; ++k)
        if (q == k) { oi = wi[k]; opf = wp[k]; }

    float ps = 0.0f;
    #pragma unroll
    for (int k = 0; k < 8; ++k) ps += wp[k];
    const float rinv = 1.0f / (ps + 1e-9f);

    if (q < KK) {
        out[(size_t)tok * KK + q]           = opf * rinv;
        out[IDX_OFF + (size_t)tok * KK + q] = (float)oi;
    }

    unsigned long long mk = 0ull;
    #pragma unroll
    for (int k = 0; k < 8; ++k) mk |= (1ull << wi[k]);

    {
        float4 a;
        a.x = ((mk >> (4 * q + 0)) & 1ull) ? 1.0f : 0.0f;
        a.y = ((mk >> (4 * q + 1)) & 1ull) ? 1.0f : 0.0f;
        a.z = ((mk >> (4 * q + 2)) & 1ull) ? 1.0f : 0.0f;
        a.w = ((mk >> (4 * q + 3)) & 1ull) ? 1.0f : 0.0f;
        *(float4*)(out + MAP_OFF + (size_t)tok * EE + 4 * q) = a;
    }

    if (blockIdx.x == 0 && tid == 0) out[AUX_OFF] = 0.0f;
}

extern "C" void kernel_launch(void* const* d_in, const int* in_sizes, int n_in,
                              void* d_out, int out_size, void* d_ws, size_t ws_size,
                              hipStream_t stream) {
    const float* hidden = (const float*)d_in[0];  // [16384, 2048] f32
    const float* gate_w = (const float*)d_in[1];  // [64, 2048] f32
    const float* bias   = (const float*)d_in[2];  // [64] f32
    float* out = (float*)d_out;
    unsigned short* ws = (unsigned short*)d_ws;   // needs 512 KB

    prep_kernel<<<128, 256, 0, stream>>>(gate_w, ws);
    router_kernel<<<TT / TB, 256, 0, stream>>>(hidden, gate_w, bias, ws, out);
}

// Round 13
// 124.690 us; speedup vs baseline: 2.2527x; 2.2527x over previous
//
#include <hip/hip_runtime.h>
#include <math.h>

// Problem constants
#define TT 16384   // tokens
#define HH 2048    // hidden
#define EE 64      // experts
#define KK 8       // top_k

#define TB 16          // tokens per block (one MFMA M-tile)
#define SCH 256        // h per superchunk
#define NSC (HH / SCH) // 8 superchunks
#define TOPC 10        // fp32 candidate count for fixup
#define MARGIN 2.5e-5f // selection-score gap below which we fp64-verify

// Output layout (flat float32):
// probs [TT][KK] | indices [TT][KK] | map [TT][EE] | aux scalar
#define IDX_OFF ((size_t)TT * KK)
#define MAP_OFF ((size_t)2 * TT * KK)
#define AUX_OFF ((size_t)2 * TT * KK + (size_t)TT * EE)

// d_ws layout (bf16 shorts): hi plane then lo plane, each WSPLANE shorts.
// Fragment-native: [m (k/32)][kq][e][8 j] (R10/R11-validated).
#define WSPLANE 131072

typedef short bf16x8 __attribute__((ext_vector_type(8)));
typedef float f32x4  __attribute__((ext_vector_type(4)));

__device__ __forceinline__ unsigned short f2bf(float x) {   // RNE fp32->bf16
    unsigned int u = __float_as_uint(x);
    u += 0x7FFFu + ((u >> 16) & 1u);
    return (unsigned short)(u >> 16);
}
__device__ __forceinline__ float bf2f(unsigned short b) {
    return __uint_as_float(((unsigned int)b) << 16);
}
__device__ __forceinline__ void cvt4(const float4 v, ushort4* hi, ushort4* lo) {
    unsigned short h0 = f2bf(v.x), h1 = f2bf(v.y),
                   h2 = f2bf(v.z), h3 = f2bf(v.w);
    *hi = make_ushort4(h0, h1, h2, h3);
    *lo = make_ushort4(f2bf(v.x - bf2f(h0)), f2bf(v.y - bf2f(h1)),
                       f2bf(v.z - bf2f(h2)), f2bf(v.w - bf2f(h3)));
}
// 8 fp32 (two float4) -> hi/lo bf16x8 fragments, in registers
__device__ __forceinline__ void cvt8(const float4 a, const float4 b,
                                     bf16x8* hi, bf16x8* lo) {
    const float v[8] = {a.x, a.y, a.z, a.w, b.x, b.y, b.z, b.w};
    bf16x8 h, l;
    #pragma unroll
    for (int i = 0; i < 8; ++i) {
        unsigned short hb = f2bf(v[i]);
        h[i] = (short)hb;
        l[i] = (short)f2bf(v[i] - bf2f(hb));
    }
    *hi = h; *lo = l;
}

// ---- prep: gate_w fp32 -> bf16 hi/lo planes, fragment-native (validated) ----
__global__ __launch_bounds__(256)
void prep_kernel(const float* __restrict__ gw, unsigned short* __restrict__ ws)
{
    const int gid = blockIdx.x * 256 + threadIdx.x;
    const int e  = gid >> 9;
    const int k  = (gid & 511) * 4;
    float4 v = *(const float4*)(gw + (size_t)e * HH + k);
    ushort4 hi, lo;
    cvt4(v, &hi, &lo);
    const int off = (k >> 5) * 2048 + ((k >> 3) & 3) * 512 + e * 8 + (k & 7);
    *(ushort4*)(ws + off)           = hi;
    *(ushort4*)(ws + WSPLANE + off) = lo;
}

__global__ __launch_bounds__(256, 4)
void router_kernel(const float* __restrict__ hidden,
                   const float* __restrict__ gate_w,
                   const float* __restrict__ bias,
                   const unsigned short* __restrict__ wsbuf,
                   float* __restrict__ out)
{
    // H tile: fp32 [16 rows][64 float4-slots]; slot s of row r stored at
    // physical slot s ^ (r&7) (write AND read sides; global columns linear).
    __shared__ __align__(16) float4 stH[16 * 64];     // 16 KB
    __shared__ __align__(16) float  lg[16 * 68 + 8];  // logit exchange

    const int tid  = threadIdx.x;
    const int tok0 = blockIdx.x * TB;

    // staging coords: thread stages row ts, logical slots xs + 16i (i=0..3)
    const int ts = tid >> 4;        // 0..15
    const int xs = tid & 15;
    const float* hsg = hidden + (size_t)(tok0 + ts) * HH + xs * 4;
    // physical slot indices (per-thread constants)
    const int p0 = ((xs + 0)  ^ (ts & 7)) + ts * 64;
    const int p1 = ((xs + 16) ^ (ts & 7)) + ts * 64;
    const int p2 = ((xs + 32) ^ (ts & 7)) + ts * 64;
    const int p3 = ((xs + 48) ^ (ts & 7)) + ts * 64;

    // fragment coords (validated): rx=lane&15 (token row / expert row),
    // kq=lane>>4, e0 = wave*16
    const int lane = tid & 63;
    const int e0   = (tid >> 6) * 16;
    const int rx   = lane & 15;
    const int kq   = lane >> 4;
    // A-read bases (float4 units): slot (c0 + kq*2 + j) ^ (rx&7) = c0 + ((kq*2+j)^(rx&7))
    const int aB0 = rx * 64 + ((kq * 2 + 0) ^ (rx & 7));
    const int aB1 = rx * 64 + ((kq * 2 + 1) ^ (rx & 7));
    const unsigned short* bBase = wsbuf + kq * 512 + (e0 + rx) * 8;

    f32x4 acc = {0.f, 0.f, 0.f, 0.f};

    // prologue: superchunk 0 loads
    float4 hv0 = *(const float4*)(hsg);
    float4 hv1 = *(const float4*)(hsg + 64);
    float4 hv2 = *(const float4*)(hsg + 128);
    float4 hv3 = *(const float4*)(hsg + 192);

    for (int sc = 0; sc < NSC; ++sc) {
        __syncthreads();   // previous superchunk's LDS reads done
        stH[p0] = hv0;
        stH[p1] = hv1;
        stH[p2] = hv2;
        stH[p3] = hv3;
        __syncthreads();   // staging visible

        // prefetch next superchunk (flies under compute)
        if (sc + 1 < NSC) {
            const float* hp = hsg + (sc + 1) * SCH;
            hv0 = *(const float4*)(hp);
            hv1 = *(const float4*)(hp + 64);
            hv2 = *(const float4*)(hp + 128);
            hv3 = *(const float4*)(hp + 192);
        }

        // compute 4 chunks of 64 h
        #pragma unroll
        for (int cc = 0; cc < 4; ++cc) {
            const int c = sc * 4 + cc;          // global chunk 0..31
            const unsigned short* bp = bBase + (size_t)(2 * c) * 2048;
            bf16x8 Bh0 = *(const bf16x8*)(bp);
            bf16x8 Bl0 = *(const bf16x8*)(bp + WSPLANE);
            bf16x8 Bh1 = *(const bf16x8*)(bp + 2048);
            bf16x8 Bl1 = *(const bf16x8*)(bp + 2048 + WSPLANE);

            float4 a0 = stH[aB0 + cc * 16];     // u=0, j=0
            float4 a1 = stH[aB1 + cc * 16];     // u=0, j=1
            float4 a2 = stH[aB0 + cc * 16 + 8]; // u=1, j=0
            float4 a3 = stH[aB1 + cc * 16 + 8]; // u=1, j=1

            bf16x8 Ah0, Al0, Ah1, Al1;
            cvt8(a0, a1, &Ah0, &Al0);
            cvt8(a2, a3, &Ah1, &Al1);

            acc = __builtin_amdgcn_mfma_f32_16x16x32_bf16(Ah0, Bl0, acc, 0, 0, 0);
            acc = __builtin_amdgcn_mfma_f32_16x16x32_bf16(Al0, Bh0, acc, 0, 0, 0);
            acc = __builtin_amdgcn_mfma_f32_16x16x32_bf16(Ah0, Bh0, acc, 0, 0, 0);
            acc = __builtin_amdgcn_mfma_f32_16x16x32_bf16(Ah1, Bl1, acc, 0, 0, 0);
            acc = __builtin_amdgcn_mfma_f32_16x16x32_bf16(Al1, Bh1, acc, 0, 0, 0);
            acc = __builtin_amdgcn_mfma_f32_16x16x32_bf16(Ah1, Bh1, acc, 0, 0, 0);
        }
    }

    // ---- logits to LDS: row = token = 4*kq + r, col = expert = e0 + rx ----
    #pragma unroll
    for (int r = 0; r < 4; ++r)
        lg[(4 * kq + r) * 68 + e0 + rx] = acc[r];
    __syncthreads();

    // ---- epilogue: 16 lanes per token (validated machinery) ----
    const int t   = tid >> 4;   // 0..15
    const int q   = tid & 15;   // lane owns experts q + 16i, i=0..3
    const int tok = tok0 + t;

    float lv[4];
    #pragma unroll
    for (int i = 0; i < 4; ++i) lv[i] = lg[t * 68 + q + 16 * i];

    float mx = lv[0];
    #pragma unroll
    for (int i = 1; i < 4; ++i) mx = fmaxf(mx, lv[i]);
    #pragma unroll
    for (int sh = 1; sh < 16; sh <<= 1) mx = fmaxf(mx, __shfl_xor(mx, sh, 64));

    float ex[4], psum = 0.0f;
    #pragma unroll
    for (int i = 0; i < 4; ++i) { ex[i] = expf(lv[i] - mx); psum += ex[i]; }
    #pragma unroll
    for (int sh = 1; sh < 16; sh <<= 1) psum += __shfl_xor(psum, sh, 64);
    const float inv = 1.0f / psum;

    float pr[4], selv[4];
    #pragma unroll
    for (int i = 0; i < 4; ++i) {
        pr[i]   = ex[i] * inv;
        selv[i] = pr[i] + bias[q + 16 * i];
    }

    float ws_[TOPC], wp[TOPC];
    int   wi[TOPC];
    #pragma unroll
    for (int k = 0; k < TOPC; ++k) {
        float bs = selv[0], bp = pr[0];
        int bi = q;
        #pragma unroll
        for (int i = 1; i < 4; ++i)
            if (selv[i] > bs) { bs = selv[i]; bp = pr[i]; bi = q + 16 * i; }
        #pragma unroll
        for (int sh = 1; sh < 16; sh <<= 1) {
            float os = __shfl_xor(bs, sh, 64);
            float op = __shfl_xor(bp, sh, 64);
            int   ob = __shfl_xor(bi, sh, 64);
            if (os > bs || (os == bs && ob < bi)) { bs = os; bp = op; bi = ob; }
        }
        ws_[k] = bs; wp[k] = bp; wi[k] = bi;
        #pragma unroll
        for (int i = 0; i < 4; ++i)
            if (q + 16 * i == bi) selv[i] = -INFINITY;
    }

    bool flag = false;
    #pragma unroll
    for (int k = 0; k < 8; ++k)
        flag = flag || (ws_[k] - ws_[k + 1] < MARGIN);

    if (flag) {   // uniform across the 16-lane token group
        const float* hrow = hidden + (size_t)tok * HH;
        const float* wr_[TOPC];
        #pragma unroll
        for (int k = 0; k < TOPC; ++k) wr_[k] = gate_w + (size_t)wi[k] * HH;

        double l64[TOPC];
        #pragma unroll
        for (int k = 0; k < TOPC; ++k) l64[k] = 0.0;

        for (int m = 0; m < 32; ++m) {
            float4 h4 = *(const float4*)(hrow + m * 64 + 4 * q);
            double h0 = h4.x, h1 = h4.y, h2 = h4.z, h3 = h4.w;
            #pragma unroll
            for (int k = 0; k < TOPC; ++k) {
                float4 w4 = *(const float4*)(wr_[k] + m * 64 + 4 * q);
                l64[k] = fma(h0, (double)w4.x, l64[k]);
                l64[k] = fma(h1, (double)w4.y, l64[k]);
                l64[k] = fma(h2, (double)w4.z, l64[k]);
                l64[k] = fma(h3, (double)w4.w, l64[k]);
            }
        }
        #pragma unroll
        for (int k = 0; k < TOPC; ++k)
            #pragma unroll
            for (int sh = 1; sh < 16; sh <<= 1)
                l64[k] += __shfl_xor(l64[k], sh, 64);

        double s64[TOPC];
        #pragma unroll
        for (int k = 0; k < TOPC; ++k)
            s64[k] = exp(l64[k] - (double)mx) * (double)inv + (double)bias[wi[k]];

        #pragma unroll
        for (int a = 0; a < 8; ++a) {
            #pragma unroll
            for (int b = a + 1; b < TOPC; ++b) {
                bool sw = (s64[b] > s64[a]) ||
                          (s64[b] == s64[a] && wi[b] < wi[a]);
                if (sw) {
                    double td = s64[a]; s64[a] = s64[b]; s64[b] = td;
                    int    ti = wi[a];  wi[a]  = wi[b];  wi[b]  = ti;
                    float  tp = wp[a];  wp[a]  = wp[b];  wp[b]  = tp;
                }
            }
        }
    }

    // ---- common write-out ----
    int oi = wi[0];
    float opf = wp[0];
    #pragma unroll
    for (int k = 1; k < 8; ++k)
        if (q == k) { oi = wi[k]; opf = wp[k]; }

    float ps = 0.0f;
    #pragma unroll
    for (int k = 0; k < 8; ++k) ps += wp[k];
    const float rinv = 1.0f / (ps + 1e-9f);

    if (q < KK) {
        out[(size_t)tok * KK + q]           = opf * rinv;
        out[IDX_OFF + (size_t)tok * KK + q] = (float)oi;
    }

    unsigned long long mk = 0ull;
    #pragma unroll
    for (int k = 0; k < 8; ++k) mk |= (1ull << wi[k]);

    {
        float4 a;
        a.x = ((mk >> (4 * q + 0)) & 1ull) ? 1.0f : 0.0f;
        a.y = ((mk >> (4 * q + 1)) & 1ull) ? 1.0f : 0.0f;
        a.z = ((mk >> (4 * q + 2)) & 1ull) ? 1.0f : 0.0f;
        a.w = ((mk >> (4 * q + 3)) & 1ull) ? 1.0f : 0.0f;
        *(float4*)(out + MAP_OFF + (size_t)tok * EE + 4 * q) = a;
    }

    if (blockIdx.x == 0 && tid == 0) out[AUX_OFF] = 0.0f;
}

extern "C" void kernel_launch(void* const* d_in, const int* in_sizes, int n_in,
                              void* d_out, int out_size, void* d_ws, size_t ws_size,
                              hipStream_t stream) {
    const float* hidden = (const float*)d_in[0];  // [16384, 2048] f32
    const float* gate_w = (const float*)d_in[1];  // [64, 2048] f32
    const float* bias   = (const float*)d_in[2];  // [64] f32
    float* out = (float*)d_out;
    unsigned short* ws = (unsigned short*)d_ws;   // needs 512 KB

    prep_kernel<<<128, 256, 0, stream>>>(gate_w, ws);
    router_kernel<<<TT / TB, 256, 0, stream>>>(hidden, gate_w, bias, ws, out);
}

// Round 14
// 111.731 us; speedup vs baseline: 2.5140x; 1.1160x over previous
//
#include <hip/hip_runtime.h>
#include <math.h>

// Problem constants
#define TT 16384   // tokens
#define HH 2048    // hidden
#define EE 64      // experts
#define KK 8       // top_k

#define TB 16          // tokens per block (one MFMA M-tile)
#define HC 64          // h per chunk (2 MFMA k-steps)
#define NCH (HH / HC)  // 32 chunks
#define TOPC 10        // fp32 candidate count for fixup
// RELATIVE margin: bf16x3 score-gap error <= (s_a+s_b) * 6.3sigma(logit err)
// (R13 post-mortem: absolute 2.5e-5 was in logit units; softmax Jacobian
//  compresses by x p, so mid-rank margins were ~12-25x too conservative ->
//  ~15-20% flag rate -> fp64 fixup dominated runtime.)
#define MARGIN_REL 8e-5f

// Output layout (flat float32):
// probs [TT][KK] | indices [TT][KK] | map [TT][EE] | aux scalar
#define IDX_OFF ((size_t)TT * KK)
#define MAP_OFF ((size_t)2 * TT * KK)
#define AUX_OFF ((size_t)2 * TT * KK + (size_t)TT * EE)

// d_ws layout (bf16 shorts): hi plane then lo plane, each WSPLANE shorts.
// Fragment-native: [m (k/32)][kq][e][8 j] (R10/R11-validated).
#define WSPLANE 131072

typedef short bf16x8 __attribute__((ext_vector_type(8)));
typedef float f32x4  __attribute__((ext_vector_type(4)));

__device__ __forceinline__ unsigned short f2bf(float x) {   // RNE fp32->bf16
    unsigned int u = __float_as_uint(x);
    u += 0x7FFFu + ((u >> 16) & 1u);
    return (unsigned short)(u >> 16);
}
__device__ __forceinline__ float bf2f(unsigned short b) {
    return __uint_as_float(((unsigned int)b) << 16);
}
__device__ __forceinline__ void cvt4(const float4 v, ushort4* hi, ushort4* lo) {
    unsigned short h0 = f2bf(v.x), h1 = f2bf(v.y),
                   h2 = f2bf(v.z), h3 = f2bf(v.w);
    *hi = make_ushort4(h0, h1, h2, h3);
    *lo = make_ushort4(f2bf(v.x - bf2f(h0)), f2bf(v.y - bf2f(h1)),
                       f2bf(v.z - bf2f(h2)), f2bf(v.w - bf2f(h3)));
}

// ---- prep: gate_w fp32 -> bf16 hi/lo planes in fragment-native layout ----
__global__ __launch_bounds__(256)
void prep_kernel(const float* __restrict__ gw, unsigned short* __restrict__ ws)
{
    const int gid = blockIdx.x * 256 + threadIdx.x;   // 0..32767 float4 slots
    const int e  = gid >> 9;          // 512 float4 per expert row
    const int k  = (gid & 511) * 4;
    float4 v = *(const float4*)(gw + (size_t)e * HH + k);
    ushort4 hi, lo;
    cvt4(v, &hi, &lo);
    const int off = (k >> 5) * 2048 + ((k >> 3) & 3) * 512 + e * 8 + (k & 7);
    *(ushort4*)(ws + off)           = hi;
    *(ushort4*)(ws + WSPLANE + off) = lo;
}

// ---- main: H staged in LDS (hi/lo, dbuf), B-frags direct from ws (L2) ----
#define CHUNK(C, HV)                                                           \
  do {                                                                         \
    const unsigned short* bp_ = bBase + (size_t)(2 * (C)) * 2048;              \
    bf16x8 Bh0 = *(const bf16x8*)(bp_);                                        \
    bf16x8 Bl0 = *(const bf16x8*)(bp_ + WSPLANE);                              \
    bf16x8 Bh1 = *(const bf16x8*)(bp_ + 2048);                                 \
    bf16x8 Bl1 = *(const bf16x8*)(bp_ + 2048 + WSPLANE);                       \
    unsigned char* buf_ = smem + ((C) & 1) * 4096;                             \
    ushort4 hi_, lo_;                                                          \
    cvt4(HV, &hi_, &lo_);                                                      \
    *(ushort4*)(buf_ + hOff)        = hi_;                                     \
    *(ushort4*)(buf_ + 2048 + hOff) = lo_;                                     \
    __syncthreads();                                                           \
    if ((C) + 2 < NCH) HV = *(const float4*)(hgp + ((C) + 2) * HC);            \
    bf16x8 Ah0 = *(const bf16x8*)(buf_ + aOff0);                               \
    bf16x8 Al0 = *(const bf16x8*)(buf_ + 2048 + aOff0);                        \
    bf16x8 Ah1 = *(const bf16x8*)(buf_ + aOff1);                               \
    bf16x8 Al1 = *(const bf16x8*)(buf_ + 2048 + aOff1);                        \
    acc = __builtin_amdgcn_mfma_f32_16x16x32_bf16(Ah0, Bl0, acc, 0, 0, 0);     \
    acc = __builtin_amdgcn_mfma_f32_16x16x32_bf16(Al0, Bh0, acc, 0, 0, 0);     \
    acc = __builtin_amdgcn_mfma_f32_16x16x32_bf16(Ah0, Bh0, acc, 0, 0, 0);     \
    acc = __builtin_amdgcn_mfma_f32_16x16x32_bf16(Ah1, Bl1, acc, 0, 0, 0);     \
    acc = __builtin_amdgcn_mfma_f32_16x16x32_bf16(Al1, Bh1, acc, 0, 0, 0);     \
    acc = __builtin_amdgcn_mfma_f32_16x16x32_bf16(Ah1, Bh1, acc, 0, 0, 0);     \
  } while (0)

__global__ __launch_bounds__(256, 4)
void router_kernel(const float* __restrict__ hidden,
                   const float* __restrict__ gate_w,
                   const float* __restrict__ bias,
                   const unsigned short* __restrict__ wsbuf,
                   float* __restrict__ out)
{
    __shared__ __align__(16) unsigned char smem[8192];

    const int tid  = threadIdx.x;
    const int tok0 = blockIdx.x * TB;

    // staging coords: thread stages H row hr, float4-slot hc4 (swizzled LDS)
    const int hr  = tid >> 4;        // 0..15
    const int hc4 = tid & 15;
    const float* hgp = hidden + (size_t)(tok0 + hr) * HH + hc4 * 4;
    const int hOff = hr * 128 + ((hc4 * 8) ^ ((hr & 7) << 4));

    // fragment coords (R9/R10-validated)
    const int lane = tid & 63;
    const int e0   = (tid >> 6) * 16;
    const int rx   = lane & 15;
    const int kq   = lane >> 4;
    const int aOff0 = rx * 128 + ((kq * 16) ^ ((rx & 7) << 4));
    const int aOff1 = aOff0 ^ 64;
    const unsigned short* bBase = wsbuf + kq * 512 + (e0 + rx) * 8;

    f32x4 acc = {0.f, 0.f, 0.f, 0.f};

    // 2-deep H prefetch ring (static names)
    float4 hvA = *(const float4*)(hgp);
    float4 hvB = *(const float4*)(hgp + HC);

    for (int c = 0; c < NCH; c += 2) {
        CHUNK(c, hvA);
        CHUNK(c + 1, hvB);
    }
    __syncthreads();   // all compute done before lg overlays buffers

    // ---- logits to LDS: row = token = 4*kq + r, col = expert = e0 + rx ----
    float* lg = (float*)smem;   // [16][68]
    #pragma unroll
    for (int r = 0; r < 4; ++r)
        lg[(4 * kq + r) * 68 + e0 + rx] = acc[r];
    __syncthreads();

    // ---- epilogue: 16 lanes per token ----
    const int t   = tid >> 4;   // 0..15
    const int q   = tid & 15;   // lane owns experts q + 16i, i=0..3
    const int tok = tok0 + t;

    float lv[4];
    #pragma unroll
    for (int i = 0; i < 4; ++i) lv[i] = lg[t * 68 + q + 16 * i];

    float mx = lv[0];
    #pragma unroll
    for (int i = 1; i < 4; ++i) mx = fmaxf(mx, lv[i]);
    #pragma unroll
    for (int sh = 1; sh < 16; sh <<= 1) mx = fmaxf(mx, __shfl_xor(mx, sh, 64));

    float ex[4], psum = 0.0f;
    #pragma unroll
    for (int i = 0; i < 4; ++i) { ex[i] = expf(lv[i] - mx); psum += ex[i]; }
    #pragma unroll
    for (int sh = 1; sh < 16; sh <<= 1) psum += __shfl_xor(psum, sh, 64);
    const float inv = 1.0f / psum;

    float pr[4], selv[4];
    #pragma unroll
    for (int i = 0; i < 4; ++i) {
        pr[i]   = ex[i] * inv;
        selv[i] = pr[i] + bias[q + 16 * i];
    }

    // top-10 candidates (fp32), strict-> with lowest-index tie-break
    float ws_[TOPC], wp[TOPC];
    int   wi[TOPC];
    #pragma unroll
    for (int k = 0; k < TOPC; ++k) {
        float bs = selv[0], bp = pr[0];
        int bi = q;
        #pragma unroll
        for (int i = 1; i < 4; ++i)
            if (selv[i] > bs) { bs = selv[i]; bp = pr[i]; bi = q + 16 * i; }
        #pragma unroll
        for (int sh = 1; sh < 16; sh <<= 1) {
            float os = __shfl_xor(bs, sh, 64);
            float op = __shfl_xor(bp, sh, 64);
            int   ob = __shfl_xor(bi, sh, 64);
            if (os > bs || (os == bs && ob < bi)) { bs = os; bp = op; bi = ob; }
        }
        ws_[k] = bs; wp[k] = bp; wi[k] = bi;
        #pragma unroll
        for (int i = 0; i < 4; ++i)
            if (q + 16 * i == bi) selv[i] = -INFINITY;
    }

    // flag: adjacent gap among ranks 1..9 within bf16x3 SCORE error
    // (relative margin: score err ~ (s_a+s_b) * logit-err; see R13 post-mortem)
    bool flag = false;
    #pragma unroll
    for (int k = 0; k < 8; ++k)
        flag = flag || (ws_[k] - ws_[k + 1] <
                        (ws_[k] + ws_[k + 1]) * MARGIN_REL + 1e-12f);

    if (flag) {   // uniform across the 16-lane token group; now ~<1% of tokens
        const float* hrow = hidden + (size_t)tok * HH;
        const float* wr_[TOPC];
        #pragma unroll
        for (int k = 0; k < TOPC; ++k) wr_[k] = gate_w + (size_t)wi[k] * HH;

        double l64[TOPC];
        #pragma unroll
        for (int k = 0; k < TOPC; ++k) l64[k] = 0.0;

        for (int m = 0; m < 32; ++m) {
            float4 h4 = *(const float4*)(hrow + m * 64 + 4 * q);
            double h0 = h4.x, h1 = h4.y, h2 = h4.z, h3 = h4.w;
            #pragma unroll
            for (int k = 0; k < TOPC; ++k) {
                float4 w4 = *(const float4*)(wr_[k] + m * 64 + 4 * q);
                l64[k] = fma(h0, (double)w4.x, l64[k]);
                l64[k] = fma(h1, (double)w4.y, l64[k]);
                l64[k] = fma(h2, (double)w4.z, l64[k]);
                l64[k] = fma(h3, (double)w4.w, l64[k]);
            }
        }
        #pragma unroll
        for (int k = 0; k < TOPC; ++k)
            #pragma unroll
            for (int sh = 1; sh < 16; sh <<= 1)
                l64[k] += __shfl_xor(l64[k], sh, 64);

        // exact-rank selection scores (common positive rescale; bias exact)
        double s64[TOPC];
        #pragma unroll
        for (int k = 0; k < TOPC; ++k)
            s64[k] = exp(l64[k] - (double)mx) * (double)inv + (double)bias[wi[k]];

        // order first 8 by (score desc, idx asc) - static indices only
        #pragma unroll
        for (int a = 0; a < 8; ++a) {
            #pragma unroll
            for (int b = a + 1; b < TOPC; ++b) {
                bool sw = (s64[b] > s64[a]) ||
                          (s64[b] == s64[a] && wi[b] < wi[a]);
                if (sw) {
                    double td = s64[a]; s64[a] = s64[b]; s64[b] = td;
                    int    ti = wi[a];  wi[a]  = wi[b];  wi[b]  = ti;
                    float  tp = wp[a];  wp[a]  = wp[b];  wp[b]  = tp;
                }
            }
        }
    }

    // ---- common write-out (wi/wp[0..7] final) ----
    int oi = wi[0];
    float opf = wp[0];
    #pragma unroll
    for (int k = 1; k < 8; ++k)
        if (q == k) { oi = wi[k]; opf = wp[k]; }

    float ps = 0.0f;
    #pragma unroll
    for (int k = 0; k < 8; ++k) ps += wp[k];
    const float rinv = 1.0f / (ps + 1e-9f);

    if (q < KK) {
        out[(size_t)tok * KK + q]           = opf * rinv;
        out[IDX_OFF + (size_t)tok * KK + q] = (float)oi;
    }

    unsigned long long mk = 0ull;
    #pragma unroll
    for (int k = 0; k < 8; ++k) mk |= (1ull << wi[k]);

    {
        float4 a;
        a.x = ((mk >> (4 * q + 0)) & 1ull) ? 1.0f : 0.0f;
        a.y = ((mk >> (4 * q + 1)) & 1ull) ? 1.0f : 0.0f;
        a.z = ((mk >> (4 * q + 2)) & 1ull) ? 1.0f : 0.0f;
        a.w = ((mk >> (4 * q + 3)) & 1ull) ? 1.0f : 0.0f;
        *(float4*)(out + MAP_OFF + (size_t)tok * EE + 4 * q) = a;
    }

    if (blockIdx.x == 0 && tid == 0) out[AUX_OFF] = 0.0f;
}

extern "C" void kernel_launch(void* const* d_in, const int* in_sizes, int n_in,
                              void* d_out, int out_size, void* d_ws, size_t ws_size,
                              hipStream_t stream) {
    const float* hidden = (const float*)d_in[0];  // [16384, 2048] f32
    const float* gate_w = (const float*)d_in[1];  // [64, 2048] f32
    const float* bias   = (const float*)d_in[2];  // [64] f32
    float* out = (float*)d_out;
    unsigned short* ws = (unsigned short*)d_ws;   // needs 512 KB

    prep_kernel<<<128, 256, 0, stream>>>(gate_w, ws);
    router_kernel<<<TT / TB, 256, 0, stream>>>(hidden, gate_w, bias, ws, out);
}